// Round 15
// baseline (1243.209 us; speedup 1.0000x reference)
//
#include <hip/hip_runtime.h>
#include <hip/hip_bf16.h>

#define NROWS 32768
#define DIM   512
#define NQ    8
#define NBINS 2048

#define MARGIN 1.0f        // ~20 sigma of bf16 phase-1 noise (validated rounds 5/7/8/9/10/12/14)

typedef __attribute__((ext_vector_type(8))) short short8v;
typedef __attribute__((ext_vector_type(4))) float f32x4;

__device__ inline unsigned short f2bf(float x) {
    __hip_bfloat16 h = __float2bfloat16(x);
    return *reinterpret_cast<unsigned short*>(&h);
}

typedef __attribute__((address_space(3))) void lds_t;
typedef __attribute__((address_space(1))) const void gbl_t;
__device__ inline void gload16(const void* g, void* l) {
    __builtin_amdgcn_global_load_lds((gbl_t*)g, (lds_t*)l, 16, 0, 0);
}

// ---------------------------------------------------------------------------
// numpy pairwise-sum combine (validated round 4)
__device__ inline float pw_combine(float s) {
#pragma unroll
    for (int m = 1; m <= 16; m <<= 1) {
        float o = __shfl_xor(s, m, 64);
        s = __fadd_rn(s, o);
    }
    return s;
}

// ---------------------------------------------------------------------------
// fused prep: codebook fp32 -> bf16 AND csq = np.sum(c*c,-1) (np-exact pairwise,
// validated round 4). One wave per codebook row; row is L1-hot for second pass.
__global__ __launch_bounds__(256) void k_prep(const float* __restrict__ cb,
                                              unsigned short* __restrict__ o,
                                              float* __restrict__ csq32) {
    int row = blockIdx.x * 4 + (threadIdx.x >> 6);
    int lane = threadIdx.x & 63;
    const float* cp = cb + (size_t)row * DIM;

    float4 a = *(const float4*)(cp + lane * 8);
    float4 b = *(const float4*)(cp + lane * 8 + 4);
    short8v v;
    v[0] = f2bf(a.x); v[1] = f2bf(a.y); v[2] = f2bf(a.z); v[3] = f2bf(a.w);
    v[4] = f2bf(b.x); v[5] = f2bf(b.y); v[6] = f2bf(b.z); v[7] = f2bf(b.w);
    *(short8v*)(o + (size_t)row * DIM + lane * 8) = v;

    float s = 0.0f;
    if (lane < 32) {
        int base = (lane >> 3) * 128 + (lane & 7);
        float e = cp[base];
        s = __fmul_rn(e, e);
#pragma unroll
        for (int m = 1; m < 16; ++m) {
            float e2 = cp[base + 8 * m];
            s = __fadd_rn(s, __fmul_rn(e2, e2));
        }
    }
    s = pw_combine(s);
    if (lane == 0) csq32[row] = s;
}

// ---------------------------------------------------------------------------
// initial residual (= hidden) + np-exact rsq + bf16 copy for the MFMA phase.
__global__ __launch_bounds__(128) void k_init(const float* __restrict__ h,
                                              float* __restrict__ rout,
                                              float* __restrict__ rsq,
                                              unsigned short* __restrict__ ahi) {
    int row = blockIdx.x;
    int t = threadIdx.x;
    __shared__ float sq[DIM];
    float4 r = *(const float4*)(h + (size_t)row * DIM + t * 4);
    *(float4*)(rout + (size_t)row * DIM + t * 4) = r;
    ushort4 hv;
    hv.x = f2bf(r.x); hv.y = f2bf(r.y); hv.z = f2bf(r.z); hv.w = f2bf(r.w);
    *(ushort4*)(ahi + (size_t)row * DIM + t * 4) = hv;
    sq[t * 4 + 0] = __fmul_rn(r.x, r.x);
    sq[t * 4 + 1] = __fmul_rn(r.y, r.y);
    sq[t * 4 + 2] = __fmul_rn(r.z, r.z);
    sq[t * 4 + 3] = __fmul_rn(r.w, r.w);
    __syncthreads();
    if (t < 32) {
        int base = (t >> 3) * 128 + (t & 7);
        float s = sq[base];
#pragma unroll
        for (int m = 1; m < 16; ++m) s = __fadd_rn(s, sq[base + 8 * m]);
        s = pw_combine(s);
        if (t == 0) rsq[row] = s;
    }
}

// ---------------------------------------------------------------------------
// phase-1: bf16 MFMA GEMM, 128x128 tile, BK=64, 4 waves x 64x64 out
// (acc[4][4], 2.0 MFMA per ds_read_b128), single-buffered staging, 4 blocks/CU
// (validated r10/r12/r14 body, 108us). r15 delta: L2-chunked XCD decode only.
__global__ __launch_bounds__(256, 4) void k_gemm(const unsigned short* __restrict__ Ahi,
                                                 const unsigned short* __restrict__ Bcb,
                                                 const float* __restrict__ csq,
                                                 float* __restrict__ partD,   // [NROWS][64]
                                                 int* __restrict__ partI) {
    __shared__ __align__(16) char lds[33792];   // union: stage A16K|B16K ; dist [128][66] f32
    __shared__ float csqS[128];

    const int tid = threadIdx.x;
    const int lane = tid & 63;
    const int w = tid >> 6;
    const int wr = w >> 1;      // 0..1 : 64-row half
    const int wc = w & 1;       // 0..1 : 64-col half

    // L2-chunked XCD decode (r15): presumed XCD = wg&7 owns 32 panels, swept as
    // two 16-panel (2MB, half-L2) chunks; each chunk passes all 16 bin tiles
    // before the next chunk starts. Bijective over (panel 0..255, T 0..15).
    const int wg = blockIdx.x;
    const int seq = wg >> 3;                               // 0..511 per-XCD order
    const int panel = (wg & 7) * 32 + (seq >> 8) * 16 + (seq & 15);   // 0..255
    const int T = (seq >> 4) & 15;                         // 0..15

    if (tid < 128) csqS[tid] = csq[T * 128 + tid];

    const char* Abase = (const char*)(Ahi + (size_t)panel * 128 * DIM);
    const char* Bbase = (const char*)(Bcb + (size_t)T * 128 * DIM);

    // per-i staging offsets: chunk swizzle (cc ^ (row&7)) on the GLOBAL source,
    // LDS dest linear (both-sides rule, validated r7+).
    int goff[4], loff[4];
#pragma unroll
    for (int i = 0; i < 4; ++i) {
        int L = i * 256 + tid;            // 0..1023
        int row = L >> 3, cc = L & 7;
        goff[i] = row * (DIM * 2) + ((cc ^ (row & 7)) << 4);
        loff[i] = L * 16;
    }

    f32x4 acc[4][4];
#pragma unroll
    for (int m = 0; m < 4; ++m)
#pragma unroll
        for (int n = 0; n < 4; ++n) acc[m][n] = (f32x4){0.f, 0.f, 0.f, 0.f};

#pragma unroll
    for (int ks = 0; ks < 8; ++ks) {
        __syncthreads();                   // all waves done reading prev tile
        const int k0b = ks * 128;
#pragma unroll
        for (int i = 0; i < 4; ++i) {
            gload16(Abase + goff[i] + k0b, lds + loff[i]);
            gload16(Bbase + goff[i] + k0b, lds + 16384 + loff[i]);
        }
        __syncthreads();                   // staged tile visible
        __builtin_amdgcn_s_setprio(1);
        const char* Ab = lds;
        const char* Bb = lds + 16384;
#pragma unroll
        for (int kk = 0; kk < 2; ++kk) {
            const int sw = (((kk * 4 + (lane >> 4)) ^ (lane & 7)) << 4);
            short8v bF[4];
#pragma unroll
            for (int n = 0; n < 4; ++n) {
                int rowB = wc * 64 + n * 16 + (lane & 15);
                bF[n] = *(const short8v*)(Bb + rowB * 128 + sw);
            }
#pragma unroll
            for (int m = 0; m < 4; ++m) {
                int rowA = wr * 64 + m * 16 + (lane & 15);
                short8v aF = *(const short8v*)(Ab + rowA * 128 + sw);
#pragma unroll
                for (int n = 0; n < 4; ++n)
                    acc[m][n] = __builtin_amdgcn_mfma_f32_16x16x32_bf16(
                        aF, bF[n], acc[m][n], 0, 0, 0);
            }
        }
        __builtin_amdgcn_s_setprio(0);
    }

    // epilogue (validated r10/r12/r14): 2 phases through [128][66], running
    // top-4 per (row,h), adjacent-lane merge -> top-4 per row per 128-bin tile.
    float td0 = 3.4e38f, td1 = 3.4e38f, td2 = 3.4e38f, td3 = 3.4e38f;
    int ti0 = 0, ti1 = 0, ti2 = 0, ti3 = 0;
    float* distf = (float*)lds;
    const int row2 = tid >> 1, h = tid & 1;

#pragma unroll
    for (int p = 0; p < 2; ++p) {
        __syncthreads();
        if (wc == p) {
#pragma unroll
            for (int m = 0; m < 4; ++m)
#pragma unroll
                for (int n = 0; n < 4; ++n)
#pragma unroll
                    for (int r = 0; r < 4; ++r) {
                        int row = wr * 64 + m * 16 + (lane >> 4) * 4 + r;
                        int cl = n * 16 + (lane & 15);                 // 0..63
                        distf[row * 66 + cl] = csqS[p * 64 + cl] - 2.0f * acc[m][n][r];
                    }
        }
        __syncthreads();
        int binb = T * 128 + p * 64 + h * 32;
        for (int c = 0; c < 32; ++c) {
            float d = distf[row2 * 66 + h * 32 + c];
            int bin = binb + c;
            if (d < td3) {
                if (d < td2) {
                    td3 = td2; ti3 = ti2;
                    if (d < td1) {
                        td2 = td1; ti2 = ti1;
                        if (d < td0) { td1 = td0; ti1 = ti0; td0 = d; ti0 = bin; }
                        else { td1 = d; ti1 = bin; }
                    } else { td2 = d; ti2 = bin; }
                } else { td3 = d; ti3 = bin; }
            }
        }
    }
#pragma unroll
    for (int j = 0; j < 4; ++j) {
        float d = __shfl_xor(j == 0 ? td0 : (j == 1 ? td1 : (j == 2 ? td2 : td3)), 1);
        int bin = __shfl_xor(j == 0 ? ti0 : (j == 1 ? ti1 : (j == 2 ? ti2 : ti3)), 1);
        if (d < td3) {
            if (d < td2) {
                td3 = td2; ti3 = ti2;
                if (d < td1) {
                    td2 = td1; ti2 = ti1;
                    if (d < td0) { td1 = td0; ti1 = ti0; td0 = d; ti0 = bin; }
                    else { td1 = d; ti1 = bin; }
                } else { td2 = d; ti2 = bin; }
            } else { td3 = d; ti3 = bin; }
        }
    }
    if (h == 0) {
        size_t g = ((size_t)panel * 128 + row2) * 64 + T * 4;
        partD[g + 0] = td0; partI[g + 0] = ti0;
        partD[g + 1] = td1; partI[g + 1] = ti1;
        partD[g + 2] = td2; partI[g + 2] = ti2;
        partD[g + 3] = td3; partI[g + 3] = ti3;
    }
}

// ---------------------------------------------------------------------------
// fused phase-2 (r15 reshape): ONE WAVE PER ROW, 4 rows per 256-thread block.
// Residual segment prefetched before the argmin (T14); argmin resolve logic
// byte-equivalent to the validated r8-r14 path; update by all 64 lanes
// (8 floats each); np-exact rsq layout unchanged.
__global__ __launch_bounds__(256) void k_ru(const float* __restrict__ partD,
                                            const int* __restrict__ partI,
                                            float* __restrict__ resid,      // in/out (== quant region)
                                            float* __restrict__ rsq,        // in/out
                                            const float* __restrict__ csq,  // stage [NBINS]
                                            const float* __restrict__ cb,   // stage fp32
                                            float* __restrict__ codeOut,
                                            unsigned short* __restrict__ ahi,
                                            const float* __restrict__ hidden,
                                            int last) {
    const int w = threadIdx.x >> 6;
    const int lane = threadIdx.x & 63;
    const int row = blockIdx.x * 4 + w;
    __shared__ float sq[4][DIM];

    const float* rp = resid + (size_t)row * DIM;
    // prefetch this lane's residual segment (HBM latency hides under argmin)
    float4 r0 = *(const float4*)(rp + lane * 8);
    float4 r1 = *(const float4*)(rp + lane * 8 + 4);

    // argmin resolve (validated margin/exact path; per-wave ballot semantics)
    float d = partD[(size_t)row * 64 + lane];
    int bi0 = partI[(size_t)row * 64 + lane];
    float bd = d; int bix = bi0;
#pragma unroll
    for (int o = 32; o > 0; o >>= 1) {
        float od = __shfl_xor(bd, o);
        int oi = __shfl_xor(bix, o);
        if (od < bd || (od == bd && oi < bix)) { bd = od; bix = oi; }
    }
    bool cand = (d <= bd + MARGIN);
    unsigned long long mask = __ballot(cand);
    int winI;
    if (__popcll(mask) == 1) {
        winI = bix;
    } else {
        float myD = 3.4e38f; int myI = 0x7fffffff;
        if (cand) {
            const float* cp = cb + (size_t)bi0 * DIM;
            float acc = 0.0f;
            for (int k = 0; k < DIM; k += 4) {
                float4 rv = *(const float4*)(rp + k);
                float4 cv = *(const float4*)(cp + k);
                acc = fmaf(rv.x, cv.x, acc);
                acc = fmaf(rv.y, cv.y, acc);
                acc = fmaf(rv.z, cv.z, acc);
                acc = fmaf(rv.w, cv.w, acc);
            }
            myD = __fadd_rn(__fsub_rn(rsq[row], __fmul_rn(2.0f, acc)), csq[bi0]);
            myI = bi0;
        }
#pragma unroll
        for (int o = 32; o > 0; o >>= 1) {
            float od = __shfl_xor(myD, o);
            int oi = __shfl_xor(myI, o);
            if (od < myD || (od == myD && oi < myI)) { myD = od; myI = oi; }
        }
        winI = myI;
    }
    if (lane == 0) codeOut[row] = (float)winI;
    const int id = winI;   // reduction leaves the same value in all lanes

    // exact fp32 residual update (validated round 4), 8 floats/lane
    const float* cp8 = cb + (size_t)id * DIM + lane * 8;
    float4 c0 = *(const float4*)cp8;
    float4 c1 = *(const float4*)(cp8 + 4);
    r0.x = __fsub_rn(r0.x, c0.x);
    r0.y = __fsub_rn(r0.y, c0.y);
    r0.z = __fsub_rn(r0.z, c0.z);
    r0.w = __fsub_rn(r0.w, c0.w);
    r1.x = __fsub_rn(r1.x, c1.x);
    r1.y = __fsub_rn(r1.y, c1.y);
    r1.z = __fsub_rn(r1.z, c1.z);
    r1.w = __fsub_rn(r1.w, c1.w);

    float* wp = resid + (size_t)row * DIM + lane * 8;
    if (last) {
        // final stage: emit quantized = hidden - r_new in place
        const float* hp = hidden + (size_t)row * DIM + lane * 8;
        float4 h0 = *(const float4*)hp;
        float4 h1 = *(const float4*)(hp + 4);
        float4 q0, q1;
        q0.x = __fsub_rn(h0.x, r0.x);
        q0.y = __fsub_rn(h0.y, r0.y);
        q0.z = __fsub_rn(h0.z, r0.z);
        q0.w = __fsub_rn(h0.w, r0.w);
        q1.x = __fsub_rn(h1.x, r1.x);
        q1.y = __fsub_rn(h1.y, r1.y);
        q1.z = __fsub_rn(h1.z, r1.z);
        q1.w = __fsub_rn(h1.w, r1.w);
        *(float4*)wp = q0;
        *(float4*)(wp + 4) = q1;
        return;   // uniform branch: all waves exit before the barrier
    }

    *(float4*)wp = r0;
    *(float4*)(wp + 4) = r1;
    short8v hv;
    hv[0] = f2bf(r0.x); hv[1] = f2bf(r0.y); hv[2] = f2bf(r0.z); hv[3] = f2bf(r0.w);
    hv[4] = f2bf(r1.x); hv[5] = f2bf(r1.y); hv[6] = f2bf(r1.z); hv[7] = f2bf(r1.w);
    *(short8v*)(ahi + (size_t)row * DIM + lane * 8) = hv;

    sq[w][lane * 8 + 0] = __fmul_rn(r0.x, r0.x);
    sq[w][lane * 8 + 1] = __fmul_rn(r0.y, r0.y);
    sq[w][lane * 8 + 2] = __fmul_rn(r0.z, r0.z);
    sq[w][lane * 8 + 3] = __fmul_rn(r0.w, r0.w);
    sq[w][lane * 8 + 4] = __fmul_rn(r1.x, r1.x);
    sq[w][lane * 8 + 5] = __fmul_rn(r1.y, r1.y);
    sq[w][lane * 8 + 6] = __fmul_rn(r1.z, r1.z);
    sq[w][lane * 8 + 7] = __fmul_rn(r1.w, r1.w);
    __syncthreads();
    if (lane < 32) {
        int base = (lane >> 3) * 128 + (lane & 7);
        float s = sq[w][base];
#pragma unroll
        for (int m = 1; m < 16; ++m) s = __fadd_rn(s, sq[w][base + 8 * m]);
        s = pw_combine(s);
        if (lane == 0) rsq[row] = s;
    }
}

// ---------------------------------------------------------------------------
extern "C" void kernel_launch(void* const* d_in, const int* in_sizes, int n_in,
                              void* d_out, int out_size, void* d_ws, size_t ws_size,
                              hipStream_t stream) {
    const float* hidden = (const float*)d_in[0];   // [NROWS][DIM]
    const float* cbs = (const float*)d_in[1];      // [NQ][NBINS][DIM]

    float* out_codes = (float*)d_out;                          // [NQ][NROWS]
    float* resid = out_codes + (size_t)NQ * NROWS;             // quant region doubles as residual

    // workspace (~67 MB)
    unsigned short* Ahi = (unsigned short*)d_ws;               // NROWS*DIM bf16
    unsigned short* Cbf = Ahi + (size_t)NROWS * DIM;           // NQ*NBINS*DIM bf16
    float* csq32 = (float*)(Cbf + (size_t)NQ * NBINS * DIM);   // NQ*NBINS
    float* rsq = csq32 + (size_t)NQ * NBINS;                   // NROWS
    float* partD = rsq + NROWS;                                // NROWS*64
    int* partI = (int*)(partD + (size_t)NROWS * 64);           // NROWS*64

    k_prep<<<NQ * NBINS / 4, 256, 0, stream>>>(cbs, Cbf, csq32);
    k_init<<<NROWS, 128, 0, stream>>>(hidden, resid, rsq, Ahi);

    for (int s = 0; s < NQ; ++s) {
        const float* cbS = cbs + (size_t)s * NBINS * DIM;
        k_gemm<<<(NROWS / 128) * (NBINS / 128), 256, 0, stream>>>(
            Ahi, Cbf + (size_t)s * NBINS * DIM, csq32 + (size_t)s * NBINS,
            partD, partI);
        k_ru<<<NROWS / 4, 256, 0, stream>>>(partD, partI, resid, rsq,
                                            csq32 + (size_t)s * NBINS, cbS,
                                            out_codes + (size_t)s * NROWS, Ahi,
                                            hidden, s == NQ - 1);
    }
}